// Round 19
// baseline (291.162 us; speedup 1.0000x reference)
//
#include <hip/hip_runtime.h>

// AdaTTSp on MI355X. B=32768, T=8, E=2, NE=16, D=H=128, L=2.
// Round 19 = r18 with kexp restructured:
//  (a) 1 barrier/tile software pipeline: GEMM2 lags GEMM1 by one tile
//      (sH double-buffered); eo stored DIRECT from acc regs (8B scattered —
//      r16 proved write-pattern neutrality); sEO+flush deleted. Barriers
//      per block 32 -> 17, each a full vmcnt drain (~0.5-1k cy) saved.
//  (b) T1 XCD-aware bijective block swizzle (512 = 8 XCD x 64): te-pair
//      blocks sharing an x-slice land on the same XCD L2.
// kprep/kmix/numerics = r18 verbatim.

typedef float f32x4 __attribute__((ext_vector_type(4)));
typedef _Float16 f16;
typedef f16 f16x8 __attribute__((ext_vector_type(8)));
typedef f16 f16x4 __attribute__((ext_vector_type(4)));

#define MFMA(a, b, c) __builtin_amdgcn_mfma_f32_16x16x32_f16(a, b, c, 0, 0, 0)
#define LOSC (1.0f / 2048.0f)
#define AS1 __attribute__((address_space(1)))
#define AS3 __attribute__((address_space(3)))

__device__ __forceinline__ void split2h(float f, f16& h, f16& l) {
  h = (f16)f;
  l = (f16)((f - (float)h) * 2048.0f);
}

// ---------------------------------------------------------------------------
// Merged prep: blocks [0,16384) cast x0 f32->fp16; blocks [16384,16912)
// transform weights (w1T/w2T single-fp16 fragments; gwT hi/lo pair).
__global__ __launch_bounds__(256) void kprep(
    const float* __restrict__ x0, const float* __restrict__ w1,
    const float* __restrict__ w2, const float* __restrict__ gw,
    f16* __restrict__ x0h, f16* __restrict__ w1T, f16* __restrict__ w2T,
    f16* __restrict__ gwT) {
  int bid = blockIdx.x;
  int tid = threadIdx.x;
  if (bid < 16384) {
    size_t i = ((size_t)bid * 256 + tid) * 8;
    f32x4 f0 = *(const f32x4*)(x0 + i);
    f32x4 f1 = *(const f32x4*)(x0 + i + 4);
    f16x8 v;
#pragma unroll
    for (int z = 0; z < 4; ++z) {
      v[z] = (f16)f0[z];
      v[4 + z] = (f16)f1[z];
    }
    *(f16x8*)(x0h + i) = v;
    return;
  }
  int idx = (bid - 16384) * 256 + tid;
  if (idx < 131072) {
    const float* src = (idx < 65536) ? w1 : w2;
    f16* dst = (idx < 65536) ? w1T : w2T;
    int i = idx & 65535;
    int lane = i & 63;
    int it = (i >> 6) & 7;
    int ks = (i >> 9) & 3;
    int q = i >> 11;
    int g = lane >> 4, le = lane & 15;
    f16x8 vh;
#pragma unroll
    for (int j = 0; j < 8; ++j)
      vh[j] = (f16)src[((size_t)q * 128 + (32 * ks + 8 * g + j)) * 128 + 16 * it + le];
    *(f16x8*)(dst + (size_t)i * 8) = vh;
  } else {
    int i = idx - 131072;  // 0..4095
    int lane = i & 63;
    int ks = (i >> 6) & 3;
    int q = (i >> 8) & 15;
    int g = lane >> 4, le = lane & 15;
    f16x8 vh, vl;
#pragma unroll
    for (int j = 0; j < 8; ++j) {
      float f = gw[((size_t)q * 128 + (32 * ks + 8 * g + j)) * 16 + le];
      f16 h, l;
      split2h(f, h, l);
      vh[j] = h;
      vl[j] = l;
    }
    *(f16x8*)(gwT + (size_t)i * 8) = vh;
    *(f16x8*)(gwT + 32768 + (size_t)i * 8) = vl;
  }
}

// ---------------------------------------------------------------------------
// Expert kernel. 512 blocks (XCD-swizzled), 256 thr (4 waves), 2 blocks/CU.
// Block = (expert, 1024 rows); 16 tiles x 64 rows, 1 barrier/tile:
//   iter i: DMA(i+1) | GEMM1(i): sX[b]->sH[b] | GEMM2(i-1): sH[b^1]->eo | bar
// Wave = (jh = wave&1: 32-row half, oh = wave>>1: 64-oc half).
// Weights in regs: w{1,2}r[4][4]; staging = global_load_lds, src-swizzled.
__global__ __launch_bounds__(256, 2) void kexp(
    const f16* __restrict__ xs, const f16* __restrict__ w1T,
    const f16* __restrict__ w2T, const float* __restrict__ b1,
    const float* __restrict__ b2, f16* __restrict__ eo, int layer) {
  __shared__ f16 sX[2][8192];  // 64 x 128, dbuf (32KB)
  __shared__ f16 sH[2][8192];  // dbuf (32KB)
  const int tid = threadIdx.x;
  const int lane = tid & 63;
  const int wave = tid >> 6;
  const int jh = wave & 1, oh = wave >> 1;
  const int g = lane >> 4, le = lane & 15;
  // XCD-aware bijective swizzle: 512 = 8 XCDs x 64 contiguous blocks.
  const int wg = (blockIdx.x & 7) * 64 + (blockIdx.x >> 3);
  const int e = wg & 15;
  const int r0 = (wg >> 4) * 1024;
  const int te = e >> 1;
  const int lx = layer * 16 + e;

  // ---- resident weight fragments: it_global = 4*oh + it ----
  f16x8 w1r[4][4], w2r[4][4];
#pragma unroll
  for (int it = 0; it < 4; ++it)
#pragma unroll
    for (int ks = 0; ks < 4; ++ks) {
      size_t fb = ((size_t)((lx * 4 + ks) * 8 + 4 * oh + it) * 64 + lane) * 8;
      w1r[it][ks] = *(const f16x8*)(w1T + fb);
      w2r[it][ks] = *(const f16x8*)(w2T + fb);
    }
  f32x4 b1v[4], b2v[4];
#pragma unroll
  for (int it = 0; it < 4; ++it) {
    b1v[it] = *(const f32x4*)(b1 + lx * 128 + 64 * oh + 16 * it + 4 * g);
    b2v[it] = *(const f32x4*)(b2 + lx * 128 + 64 * oh + 16 * it + 4 * g);
  }

  // ---- direct global->LDS staging: wave covers rows 16w..16w+15 ----
  auto stage_gl = [&](int buf, int tile) {
#pragma unroll
    for (int i = 0; i < 4; ++i) {
      int row = 16 * wave + 4 * i + (lane >> 4);
      int gc = lane & 15;
      const f16* src = xs + ((size_t)(r0 + tile * 64 + row) * 8 + te) * 128 +
                       (gc ^ (row & 7)) * 8;
      f16* dst = &sX[buf][(16 * wave + 4 * i) * 128];
      __builtin_amdgcn_global_load_lds((const AS1 void*)src, (AS3 void*)dst,
                                       16, 0, 0);
    }
  };

  // ---- GEMM1(tile): sX[b] -> sH[b] ----
  auto gemm1 = [&](int b) {
    f32x4 a[4][2];
#pragma unroll
    for (int it = 0; it < 4; ++it)
#pragma unroll
      for (int j2 = 0; j2 < 2; ++j2) a[it][j2] = f32x4{0.f, 0.f, 0.f, 0.f};
#pragma unroll
    for (int ks = 0; ks < 4; ++ks)
#pragma unroll
      for (int j2 = 0; j2 < 2; ++j2) {
        int brow = 32 * jh + 16 * j2 + le;
        f16x8 bf = *(const f16x8*)(&sX[b][brow * 128 + 8 * ((4 * ks + g) ^ (brow & 7))]);
#pragma unroll
        for (int it = 0; it < 4; ++it)
          a[it][j2] = MFMA(w1r[it][ks], bf, a[it][j2]);
      }
#pragma unroll
    for (int it = 0; it < 4; ++it)
#pragma unroll
      for (int j2 = 0; j2 < 2; ++j2) {
        int brow = 32 * jh + 16 * j2 + le;
        f16x4 hv;
#pragma unroll
        for (int r = 0; r < 4; ++r)
          hv[r] = (f16)fmaxf(a[it][j2][r] + b1v[it][r], 0.f);
        int gran = 8 * oh + 2 * it + (g >> 1);
        *(f16x4*)(&sH[b][brow * 128 + 8 * (gran ^ (brow & 7)) + 4 * (g & 1)]) = hv;
      }
  };

  // ---- GEMM2(tile): sH[hb] -> direct eo stores (natural e-major layout) ----
  auto gemm2 = [&](int tile, int hb) {
    f32x4 a[4][2];
#pragma unroll
    for (int it = 0; it < 4; ++it)
#pragma unroll
      for (int j2 = 0; j2 < 2; ++j2) a[it][j2] = f32x4{0.f, 0.f, 0.f, 0.f};
#pragma unroll
    for (int ks = 0; ks < 4; ++ks)
#pragma unroll
      for (int j2 = 0; j2 < 2; ++j2) {
        int brow = 32 * jh + 16 * j2 + le;
        f16x8 bf = *(const f16x8*)(&sH[hb][brow * 128 + 8 * ((4 * ks + g) ^ (brow & 7))]);
#pragma unroll
        for (int it = 0; it < 4; ++it)
          a[it][j2] = MFMA(w2r[it][ks], bf, a[it][j2]);
      }
#pragma unroll
    for (int it = 0; it < 4; ++it)
#pragma unroll
      for (int j2 = 0; j2 < 2; ++j2) {
        int grow = r0 + tile * 64 + 32 * jh + 16 * j2 + le;
        f16x4 ev;
#pragma unroll
        for (int r = 0; r < 4; ++r)
          ev[r] = (f16)fmaxf(a[it][j2][r] + b2v[it][r], 0.f);
        *(f16x4*)(eo + ((size_t)e * 32768 + grow) * 128 + 64 * oh + 16 * it +
                  4 * g) = ev;
      }
  };

  stage_gl(0, 0);
  __syncthreads();

  for (int i = 0; i < 16; ++i) {
    const int b = i & 1;
    if (i < 15) stage_gl(b ^ 1, i + 1);
    gemm1(b);
    if (i > 0) gemm2(i - 1, b ^ 1);
    __syncthreads();  // sH[b] visible; DMA(i+1) drained; sX[b^1] ready
  }
  gemm2(15, 1);

  // keep weights live across the loop (anti-rematerialization)
#pragma unroll
  for (int it = 0; it < 4; ++it)
#pragma unroll
    for (int ks = 0; ks < 4; ++ks) {
      asm volatile("" : "+v"(w1r[it][ks]));
      asm volatile("" : "+v"(w2r[it][ks]));
    }
}

// ---------------------------------------------------------------------------
// Gate + mix kernel (r17/r18 verbatim). grid = 1024 blocks (32 rows), 512 thr.
__global__ __launch_bounds__(512, 4) void kmix(
    const f16* __restrict__ xs, const f16* __restrict__ gwT,
    const float* __restrict__ gb, const float* __restrict__ sw,
    const f16* __restrict__ eo, f16* __restrict__ x1out,
    float* __restrict__ fout, int layer) {
  __shared__ float sG[8 * 16 * 32];  // [t][e][row32] 16KB
  const int tid = threadIdx.x;
  const int lane = tid & 63;
  const int t = tid >> 6;
  const int g = lane >> 4, le = lane & 15;
  const int r0 = blockIdx.x * 32;
  const int lt = layer * 8 + t;

  {  // ---- gates ----
    f32x4 l1[2], l2[2];
#pragma unroll
    for (int j = 0; j < 2; ++j) {
      l1[j] = f32x4{0.f, 0.f, 0.f, 0.f};
      l2[j] = f32x4{0.f, 0.f, 0.f, 0.f};
    }
#pragma unroll
    for (int ks = 0; ks < 4; ++ks) {
      size_t fb = ((size_t)(lt * 4 + ks) * 64 + lane) * 8;
      f16x8 ah = *(const f16x8*)(gwT + fb);
      f16x8 al = *(const f16x8*)(gwT + 32768 + fb);
#pragma unroll
      for (int j = 0; j < 2; ++j) {
        f16x8 bf = *(const f16x8*)(xs + ((size_t)(r0 + 16 * j + le) * 8 + t) * 128 +
                                   32 * ks + 8 * g);
        l1[j] = MFMA(ah, bf, l1[j]);
        l2[j] = MFMA(al, bf, l2[j]);
      }
    }
#pragma unroll
    for (int j = 0; j < 2; ++j) {
      float zb[4];
#pragma unroll
      for (int r = 0; r < 4; ++r)
        zb[r] = l1[j][r] + l2[j][r] * LOSC + gb[lt * 16 + 4 * g + r];
      float m4 = fmaxf(fmaxf(zb[0], zb[1]), fmaxf(zb[2], zb[3]));
      m4 = fmaxf(m4, __shfl_xor(m4, 16, 64));
      m4 = fmaxf(m4, __shfl_xor(m4, 32, 64));
      float p4[4], s4 = 0.f;
#pragma unroll
      for (int r = 0; r < 4; ++r) {
        p4[r] = __expf(zb[r] - m4);
        s4 += p4[r];
      }
      s4 += __shfl_xor(s4, 16, 64);
      s4 += __shfl_xor(s4, 32, 64);
      float inv = 1.f / s4;
#pragma unroll
      for (int r = 0; r < 4; ++r)
        sG[(t * 16 + 4 * g + r) * 32 + 16 * j + le] = p4[r] * inv;
    }
  }
  __syncthreads();

  // ---- mix ----
  const int lrow = tid >> 4;
  const int grow = r0 + lrow;
  const int cq = (tid & 15) * 8;
  f32x4 am[8][2];
#pragma unroll
  for (int tt = 0; tt < 8; ++tt)
#pragma unroll
    for (int k = 0; k < 2; ++k) am[tt][k] = f32x4{0.f, 0.f, 0.f, 0.f};

  for (int ee = 0; ee < 16; ++ee) {
    const int tte = ee >> 1, eh = ee & 1;
    f16x8 ev = *(const f16x8*)(eo + ((size_t)ee * 32768 + grow) * 128 + cq);
    float evf[8];
#pragma unroll
    for (int z = 0; z < 8; ++z) evf[z] = (float)ev[z];
    float ssew = sw[(layer * 8 + tte) * 2 + eh];
#pragma unroll
    for (int tt = 0; tt < 8; ++tt) {
      float coef = sG[(tt * 16 + ee) * 32 + lrow] + (tt == tte ? ssew : 0.f);
#pragma unroll
      for (int z = 0; z < 8; ++z)
        am[tt][z >> 2][z & 3] = fmaf(coef, evf[z], am[tt][z >> 2][z & 3]);
    }
  }
#pragma unroll
  for (int tt = 0; tt < 8; ++tt) {
    size_t off = ((size_t)grow * 8 + tt) * 128 + cq;
    if (layer == 0) {
      f16x8 hv;
#pragma unroll
      for (int z = 0; z < 8; ++z) hv[z] = (f16)am[tt][z >> 2][z & 3];
      *(f16x8*)(x1out + off) = hv;
    } else {
      *(f32x4*)(fout + off) = am[tt][0];
      *(f32x4*)(fout + off + 4) = am[tt][1];
    }
  }
}

// ---------------------------------------------------------------------------
extern "C" void kernel_launch(void* const* d_in, const int* in_sizes, int n_in,
                              void* d_out, int out_size, void* d_ws, size_t ws_size,
                              hipStream_t stream) {
  const float* x0 = (const float*)d_in[0];
  const float* w1 = (const float*)d_in[1];
  const float* b1 = (const float*)d_in[2];
  const float* w2 = (const float*)d_in[3];
  const float* b2 = (const float*)d_in[4];
  const float* gw = (const float*)d_in[5];
  const float* gb = (const float*)d_in[6];
  const float* sw = (const float*)d_in[7];

  // ws bytes: w1T [0,1MB) | w2T [1MB,2MB) | gwT pair [2MB,+128KB)
  // | x0h fp16 [4MB,+64MB) | x1h fp16 [68MB,+64MB) | eo fp16 [132MB,+128MB)
  f16* w1T = (f16*)d_ws;
  f16* w2T = (f16*)((char*)d_ws + 1048576);
  f16* gwT = (f16*)((char*)d_ws + 2097152);
  f16* x0h = (f16*)((char*)d_ws + 4194304);
  f16* x1h = (f16*)((char*)d_ws + 71303168);
  f16* eo = (f16*)((char*)d_ws + 138412032);
  float* out = (float*)d_out;

  kprep<<<16912, 256, 0, stream>>>(x0, w1, w2, gw, x0h, w1T, w2T, gwT);

  kexp<<<512, 256, 0, stream>>>(x0h, w1T, w2T, b1, b2, eo, 0);
  kmix<<<1024, 512, 0, stream>>>(x0h, gwT, gb, sw, eo, x1h, nullptr, 0);
  kexp<<<512, 256, 0, stream>>>(x1h, w1T, w2T, b1, b2, eo, 1);
  kmix<<<1024, 512, 0, stream>>>(x1h, gwT, gb, sw, eo, nullptr, out, 1);
}